// Round 8
// baseline (226.660 us; speedup 1.0000x reference)
//
#include <hip/hip_runtime.h>

#define INF_BITS 0x7F800000u

typedef float f32x4 __attribute__((ext_vector_type(4)));
typedef __bf16 bf16x8 __attribute__((ext_vector_type(8)));
typedef unsigned short u16x8 __attribute__((ext_vector_type(8)));
typedef unsigned int u32x4 __attribute__((ext_vector_type(4)));

static __device__ __forceinline__ unsigned short f2bf(float f) {
  unsigned int u = __float_as_uint(f);
  return (unsigned short)((u + 0x7FFFu + ((u >> 16) & 1u)) >> 16);  // RTNE
}

// ---- init: +inf min-dists; zero xT pad rows; +inf x2 pad ----
__global__ void k_init(unsigned int* __restrict__ outu, u32x4* __restrict__ xTpad,
                       unsigned int* __restrict__ x2u) {
  int i = blockIdx.x * blockDim.x + threadIdx.x;
  if (i < 64000) outu[6400 + i] = INF_BITS;
  if (i < 32768) xTpad[i] = (u32x4){0u, 0u, 0u, 0u};  // rows 6272..6399 of xT
  if (i < 128) x2u[6272 + i] = INF_BITS;
}

// ---- protos (2000x2048 f32) -> pT (2048x2048 bf16, pad rows zero) + p2 ----
__global__ __launch_bounds__(256) void k_prep_p(const float* __restrict__ protos,
                                                unsigned short* __restrict__ pT,
                                                float* __restrict__ p2) {
  const int row = blockIdx.x;   // 2048
  const int tid = threadIdx.x;  // 256
  __shared__ float red[4];
  float s = 0.f;
  u16x8 h = (u16x8){0, 0, 0, 0, 0, 0, 0, 0};
  if (row < 2000) {
    const float* src = protos + (size_t)row * 2048 + tid * 8;
    f32x4 a = *(const f32x4*)src;
    f32x4 c = *(const f32x4*)(src + 4);
    h = (u16x8){f2bf(a.x), f2bf(a.y), f2bf(a.z), f2bf(a.w),
                f2bf(c.x), f2bf(c.y), f2bf(c.z), f2bf(c.w)};
    s = a.x * a.x + a.y * a.y + a.z * a.z + a.w * a.w +
        c.x * c.x + c.y * c.y + c.z * c.z + c.w * c.w;
  }
  *(u16x8*)(pT + (size_t)row * 2048 + tid * 8) = h;
  #pragma unroll
  for (int off = 32; off; off >>= 1) s += __shfl_xor(s, off);
  if ((tid & 63) == 0) red[tid >> 6] = s;
  __syncthreads();
  if (tid == 0) p2[row] = red[0] + red[1] + red[2] + red[3];
}

// ---- x (b,k,n) f32 -> xT[(b*196+n)*2048+k] bf16 + x2 partials ----
__global__ __launch_bounds__(256) void k_prep_x(const float* __restrict__ x,
                                                unsigned short* __restrict__ xT,
                                                float* __restrict__ x2p) {
  const int kt = blockIdx.x;  // 32
  const int b  = blockIdx.y;  // 32
  const int tid = threadIdx.x;
  __shared__ unsigned short Ls[64][201];
  const float* src = x + ((size_t)b * 2048 + (size_t)kt * 64) * 196;
  for (int idx = tid; idx < 64 * 196; idx += 256) {
    int kk = idx / 196, n = idx - kk * 196;
    Ls[kk][n] = f2bf(src[idx]);
  }
  __syncthreads();
  if (tid < 196) {  // x2 partial from bf16 values (column tid)
    float s = 0.f;
    #pragma unroll
    for (int j = 0; j < 64; ++j) {
      float v = __uint_as_float((unsigned int)Ls[j][tid] << 16);
      s += v * v;
    }
    x2p[kt * 6272 + b * 196 + tid] = s;
  }
  unsigned short* dstb = xT + (size_t)b * 196 * 2048 + kt * 64;
  for (int idx = tid; idx < 196 * 32; idx += 256) {
    int n = idx >> 5, j = idx & 31;
    unsigned int v = (unsigned int)Ls[2 * j][n] |
                     ((unsigned int)Ls[2 * j + 1][n] << 16);
    *(unsigned int*)(dstb + (size_t)n * 2048 + 2 * j) = v;
  }
}

__global__ void k_x2r(const float* __restrict__ x2p, float* __restrict__ x2) {
  int i = blockIdx.x * blockDim.x + threadIdx.x;
  if (i >= 6272) return;
  float s = 0.f;
  #pragma unroll
  for (int c = 0; c < 32; ++c) s += x2p[c * 6272 + i];
  x2[i] = s;
}

// ---- main GEMM: 256x256 tile, NO LDS, NO barriers: free-running waves,
// fragments loaded straight from global (L1/L2-resident), register dbuf ----
__global__ __launch_bounds__(512, 2) void k_main(
    const unsigned short* __restrict__ pT, const unsigned short* __restrict__ xT,
    const float* __restrict__ p2, const float* __restrict__ x2,
    unsigned int* __restrict__ outu) {
  // XCD swizzle: XCD x owns wgid [25x, 25x+25) = 2 ptiles x ~12.5 mtiles
  const int orig = blockIdx.x;
  const int wgid = (orig & 7) * 25 + (orig >> 3);
  const int ptpair = wgid / 50;
  const int rem = wgid - ptpair * 50;
  const int ptile = ptpair * 2 + (rem & 1);  // 0..7
  const int mtile = rem >> 1;                // 0..24
  const int p0 = ptile * 256;
  const int m0 = mtile * 256;
  const int tid = threadIdx.x;
  const int lane = tid & 63;
  const int w = tid >> 6;   // 8 waves
  const int wp = w >> 2;    // A half (128 rows)
  const int wn = w & 3;     // B quarter (64 cols)
  const int lr = lane & 15;
  const int lg = lane >> 4;

  f32x4 acc[8][4];
  #pragma unroll
  for (int mi = 0; mi < 8; ++mi)
    #pragma unroll
    for (int ni = 0; ni < 4; ++ni)
      acc[mi][ni] = (f32x4){0.f, 0.f, 0.f, 0.f};

  // per-lane fragment base addresses (k-contiguous rows; same k-convention
  // for A and B, so the MFMA dot is consistent — layout as rounds 5-7)
  const char* aB = (const char*)pT + (size_t)(p0 + wp * 128 + lr) * 4096 + lg * 16;
  const char* bB = (const char*)xT + (size_t)(m0 + wn * 64 + lr) * 4096 + lg * 16;

#define LOAD_A(dst_, ks_)                                                      \
    _Pragma("unroll")                                                          \
    for (int mi_ = 0; mi_ < 8; ++mi_)                                          \
      dst_[mi_] = *(const bf16x8*)(aB + mi_ * 65536 + (size_t)(ks_) * 64);
#define LOAD_B(dst_, ks_)                                                      \
    _Pragma("unroll")                                                          \
    for (int ni_ = 0; ni_ < 4; ++ni_)                                          \
      dst_[ni_] = *(const bf16x8*)(bB + ni_ * 65536 + (size_t)(ks_) * 64);
#define MFMA_ALL(af_, bf_) do { __builtin_amdgcn_s_setprio(1);                 \
    _Pragma("unroll")                                                          \
    for (int mi_ = 0; mi_ < 8; ++mi_)                                          \
      _Pragma("unroll")                                                        \
      for (int ni_ = 0; ni_ < 4; ++ni_)                                        \
        acc[mi_][ni_] = __builtin_amdgcn_mfma_f32_16x16x32_bf16(               \
            af_[mi_], bf_[ni_], acc[mi_][ni_], 0, 0, 0);                       \
    __builtin_amdgcn_s_setprio(0); } while (0)

  // register double-buffer: even/odd named sets (all indices compile-time)
  bf16x8 aE[8], bE[4], aO[8], bO[4];
  LOAD_A(aE, 0); LOAD_B(bE, 0);
  LOAD_A(aO, 1); LOAD_B(bO, 1);

  #pragma unroll 1
  for (int ks = 0; ks < 62; ks += 2) {
    MFMA_ALL(aE, bE);                       // waits only on aE/bE batch
    LOAD_A(aE, ks + 2); LOAD_B(bE, ks + 2); // refill even set
    MFMA_ALL(aO, bO);
    LOAD_A(aO, ks + 3); LOAD_B(bO, ks + 3); // refill odd set
  }
  MFMA_ALL(aE, bE);   // ks = 62
  MFMA_ALL(aO, bO);   // ks = 63
#undef MFMA_ALL
#undef LOAD_A
#undef LOAD_B

  // epilogue: d2 = x2[m] + p2[p] - 2*dot ; per-wave 64-col window, <=2 batches
  const int wm_base = m0 + wn * 64;
  const int b_lo = wm_base / 196;
  int b_hi = (wm_base + 63) / 196;
  if (b_hi > 31) b_hi = 31;
  const bool wave_ok = (b_lo < 32);
  float x2v[4];
  int seg0[4];
  #pragma unroll
  for (int ni = 0; ni < 4; ++ni) {
    const int m = wm_base + ni * 16 + lr;  // D col = lane&15
    x2v[ni] = x2[m];
    seg0[ni] = ((m / 196) == b_lo);
  }
  const float INF = __uint_as_float(INF_BITS);
  #pragma unroll
  for (int mi = 0; mi < 8; ++mi) {
    const int prow = p0 + wp * 128 + mi * 16 + 4 * lg;  // D row = 4*(lane>>4)+j
    #pragma unroll
    for (int j = 0; j < 4; ++j) {
      const int p = prow + j;
      const float pp = p2[p];
      float ma = INF, mb = INF;
      #pragma unroll
      for (int ni = 0; ni < 4; ++ni) {
        const float d2 = x2v[ni] + pp - 2.f * acc[mi][ni][j];
        ma = fminf(ma, seg0[ni] ? d2 : INF);
        mb = fminf(mb, seg0[ni] ? INF : d2);
      }
      #pragma unroll
      for (int off = 1; off < 16; off <<= 1) {
        ma = fminf(ma, __shfl_xor(ma, off));
        mb = fminf(mb, __shfl_xor(mb, off));
      }
      if (lr == 0 && p < 2000 && wave_ok) {
        atomicMin(&outu[6400 + b_lo * 2000 + p], __float_as_uint(fmaxf(ma, 0.f)));
        if (b_hi != b_lo)
          atomicMin(&outu[6400 + b_hi * 2000 + p], __float_as_uint(fmaxf(mb, 0.f)));
      }
    }
  }
}

// ---- post: d = sqrt(max(d2,1e-12)) in place; sim -> simbuf ----
__global__ void k_post(float* __restrict__ out, float* __restrict__ simbuf) {
  int i = blockIdx.x * blockDim.x + threadIdx.x;
  if (i >= 64000) return;
  float d2 = out[6400 + i];
  float d = sqrtf(fmaxf(d2, 1e-12f));
  out[6400 + i] = d;
  simbuf[i] = logf((d + 1.0f) / (d + 1e-7f));
}

// ---- scores: one wave per (b, class) pair ----
__global__ __launch_bounds__(256) void k_scores(const float* __restrict__ fc_w,
                                                const float* __restrict__ simbuf,
                                                float* __restrict__ out) {
  const int id = blockIdx.x * 4 + (threadIdx.x >> 6);  // 0..6399
  const int lane = threadIdx.x & 63;
  const int b = id / 200;
  const int c = id - b * 200;
  const f32x4* sv = (const f32x4*)(simbuf + (size_t)b * 2000);
  const f32x4* wv = (const f32x4*)(fc_w + (size_t)c * 2000);
  float s = 0.f;
  #pragma unroll
  for (int it = 0; it < 8; ++it) {
    int i = lane + it * 64;
    if (i < 500) {
      f32x4 a = sv[i], w4 = wv[i];
      s += a.x * w4.x + a.y * w4.y + a.z * w4.z + a.w * w4.w;
    }
  }
  #pragma unroll
  for (int off = 32; off; off >>= 1) s += __shfl_xor(s, off);
  if (lane == 0) out[b * 200 + c] = s;
}

extern "C" void kernel_launch(void* const* d_in, const int* in_sizes, int n_in,
                              void* d_out, int out_size, void* d_ws, size_t ws_size,
                              hipStream_t stream) {
  const float* x      = (const float*)d_in[0];  // (32, 2048, 14, 14) f32
  const float* protos = (const float*)d_in[1];  // (1, 2000, 2048) f32
  const float* fc_w   = (const float*)d_in[2];  // (200, 2000) f32
  float* out = (float*)d_out;                   // 6400 scores + 64000 min-dists

  char* wsb = (char*)d_ws;
  unsigned short* pT = (unsigned short*)wsb;              // 2048*4096B  = 8388608
  unsigned short* xT = (unsigned short*)(wsb + 8388608);  // 6400*4096B  = 26214400
  float* p2   = (float*)(wsb + 34603008);                 // 2048 f32
  float* x2   = (float*)(wsb + 34611200);                 // 6400 f32 (pad +inf)
  float* x2p  = (float*)(wsb + 34636800);                 // 32*6272 f32
  float* simb = (float*)(wsb + 34636800);                 // aliases x2p (used later)

  k_init<<<256, 256, 0, stream>>>((unsigned int*)d_out,
                                  (u32x4*)(wsb + 8388608 + (size_t)6272 * 4096),
                                  (unsigned int*)x2);
  k_prep_p<<<2048, 256, 0, stream>>>(protos, pT, p2);
  k_prep_x<<<dim3(32, 32), 256, 0, stream>>>(x, xT, x2p);
  k_x2r<<<25, 256, 0, stream>>>(x2p, x2);
  k_main<<<200, 512, 0, stream>>>(pT, xT, p2, x2, (unsigned int*)d_out);
  k_post<<<250, 256, 0, stream>>>(out, simb);
  k_scores<<<1600, 256, 0, stream>>>(fc_w, simb, out);
}

// Round 9
// 151.814 us; speedup vs baseline: 1.4930x; 1.4930x over previous
//
#include <hip/hip_runtime.h>

#define INF_BITS 0x7F800000u
#define AS1 __attribute__((address_space(1)))
#define AS3 __attribute__((address_space(3)))

typedef float f32x4 __attribute__((ext_vector_type(4)));
typedef __bf16 bf16x8 __attribute__((ext_vector_type(8)));
typedef unsigned short u16x4 __attribute__((ext_vector_type(4)));
typedef unsigned short u16x8 __attribute__((ext_vector_type(8)));
typedef unsigned int u32x4 __attribute__((ext_vector_type(4)));

static __device__ __forceinline__ unsigned short f2bf(float f) {
  unsigned int u = __float_as_uint(f);
  return (unsigned short)((u + 0x7FFFu + ((u >> 16) & 1u)) >> 16);  // RTNE
}

// ---- protos (2000x2048 f32) -> pT (2048x2048 bf16, pad rows zero) + p2 ----
// also initializes out's min-distance region to +inf (blocks 0..249)
__global__ __launch_bounds__(256) void k_prep_p(const float* __restrict__ protos,
                                                unsigned short* __restrict__ pT,
                                                float* __restrict__ p2,
                                                unsigned int* __restrict__ outu) {
  const int row = blockIdx.x;   // 2048
  const int tid = threadIdx.x;  // 256
  const int gi = row * 256 + tid;
  if (gi < 64000) outu[6400 + gi] = INF_BITS;
  __shared__ float red[4];
  float s = 0.f;
  u16x8 h = (u16x8){0, 0, 0, 0, 0, 0, 0, 0};
  if (row < 2000) {
    const float* src = protos + (size_t)row * 2048 + tid * 8;
    f32x4 a = *(const f32x4*)src;
    f32x4 c = *(const f32x4*)(src + 4);
    h = (u16x8){f2bf(a.x), f2bf(a.y), f2bf(a.z), f2bf(a.w),
                f2bf(c.x), f2bf(c.y), f2bf(c.z), f2bf(c.w)};
    s = a.x * a.x + a.y * a.y + a.z * a.z + a.w * a.w +
        c.x * c.x + c.y * c.y + c.z * c.z + c.w * c.w;
  }
  *(u16x8*)(pT + (size_t)row * 2048 + tid * 8) = h;
  #pragma unroll
  for (int off = 32; off; off >>= 1) s += __shfl_xor(s, off);
  if ((tid & 63) == 0) red[tid >> 6] = s;
  __syncthreads();
  if (tid == 0) p2[row] = red[0] + red[1] + red[2] + red[3];
}

// ---- x (b,k,n) f32 -> xT[(b*196+n)*2048+k] bf16 + x2 partials ----
// vectorized: f32x4 loads, u32x4 (16B) transposed writes. b==32 blocks do pads.
__global__ __launch_bounds__(256) void k_prep_x(const float* __restrict__ x,
                                                unsigned short* __restrict__ xT,
                                                float* __restrict__ x2p,
                                                float* __restrict__ x2) {
  const int kt = blockIdx.x;  // 32
  const int b  = blockIdx.y;  // 33: b==32 -> padding work
  const int tid = threadIdx.x;
  if (b == 32) {
    // zero xT rows 6272..6399 (128 * 4096 B = 32768 u32x4), split over 32 blocks
    u32x4* pad = (u32x4*)(xT + (size_t)6272 * 2048);
    #pragma unroll
    for (int j = tid; j < 1024; j += 256)
      pad[kt * 1024 + j] = (u32x4){0u, 0u, 0u, 0u};
    if (kt == 0 && tid < 128) x2[6272 + tid] = __uint_as_float(INF_BITS);
    return;
  }
  __shared__ unsigned short Ls[64][204];  // stride 204: 8B-aligned u16x4 stores
  const float* src = x + ((size_t)b * 2048 + (size_t)kt * 64) * 196;
  // load [64][196] f32 as 3136 f32x4 chunks (rows are 16B-aligned: 196*4=784)
  for (int idx = tid; idx < 3136; idx += 256) {
    const int kk = idx / 49, c4 = idx - kk * 49;
    f32x4 v = *(const f32x4*)(src + (size_t)kk * 196 + c4 * 4);
    *(u16x4*)&Ls[kk][c4 * 4] = (u16x4){f2bf(v.x), f2bf(v.y), f2bf(v.z), f2bf(v.w)};
  }
  __syncthreads();
  if (tid < 196) {  // x2 partial from bf16 values (column tid)
    float s = 0.f;
    #pragma unroll
    for (int j = 0; j < 64; ++j) {
      float v = __uint_as_float((unsigned int)Ls[j][tid] << 16);
      s += v * v;
    }
    x2p[kt * 6272 + b * 196 + tid] = s;
  }
  // transposed write-out: per n, 8 x u32x4 (16B) -> 128B contiguous per n
  unsigned short* dstb = xT + (size_t)b * 196 * 2048 + kt * 64;
  for (int idx = tid; idx < 1568; idx += 256) {
    const int n = idx >> 3, q = idx & 7;
    const int k0 = q * 8;
    u32x4 v;
    v.x = (unsigned int)Ls[k0 + 0][n] | ((unsigned int)Ls[k0 + 1][n] << 16);
    v.y = (unsigned int)Ls[k0 + 2][n] | ((unsigned int)Ls[k0 + 3][n] << 16);
    v.z = (unsigned int)Ls[k0 + 4][n] | ((unsigned int)Ls[k0 + 5][n] << 16);
    v.w = (unsigned int)Ls[k0 + 6][n] | ((unsigned int)Ls[k0 + 7][n] << 16);
    *(u32x4*)(dstb + (size_t)n * 2048 + k0) = v;
  }
}

__global__ void k_x2r(const float* __restrict__ x2p, float* __restrict__ x2) {
  int i = blockIdx.x * blockDim.x + threadIdx.x;
  if (i >= 6272) return;
  float s = 0.f;
  #pragma unroll
  for (int c = 0; c < 32; ++c) s += x2p[c * 6272 + i];
  x2[i] = s;
}

// ---- main GEMM: 256x256 tile, BK=64, 8 waves, m201-style 4-phase/K-tile ----
// (verbatim round-5 kernel: best measured configuration, 72 us)
__global__ __launch_bounds__(512, 2) void k_main(
    const unsigned short* __restrict__ pT, const unsigned short* __restrict__ xT,
    const float* __restrict__ p2, const float* __restrict__ x2,
    unsigned int* __restrict__ outu) {
  const int orig = blockIdx.x;
  const int wgid = (orig & 7) * 25 + (orig >> 3);
  const int ptpair = wgid / 50;
  const int rem = wgid - ptpair * 50;
  const int ptile = ptpair * 2 + (rem & 1);  // 0..7
  const int mtile = rem >> 1;                // 0..24
  const int p0 = ptile * 256;
  const int m0 = mtile * 256;
  const int tid = threadIdx.x;
  const int lane = tid & 63;
  const int w = tid >> 6;   // 8 waves
  const int wp = w >> 2;    // A half (128 rows)
  const int wn = w & 3;     // B quarter (64 rows)
  const int lr = lane & 15;
  const int lg = lane >> 4;

  __shared__ __align__(16) char S[131072];  // A[2]:0..64K, B[2]:64K..128K

  f32x4 acc[8][4];
  #pragma unroll
  for (int mi = 0; mi < 8; ++mi)
    #pragma unroll
    for (int ni = 0; ni < 4; ++ni)
      acc[mi][ni] = (f32x4){0.f, 0.f, 0.f, 0.f};

  const int rowbase = tid >> 3;                       // 0..63
  const int chunk = (tid & 7) ^ (rowbase & 7);        // involution
  const char* gA = (const char*)pT + (size_t)(p0 + rowbase) * 4096 + chunk * 16;
  const char* gB = (const char*)xT + (size_t)(m0 + rowbase) * 4096 + chunk * 16;
  const int wbase = w * 1024;

#define STAGE_A(c_, kt_, h_) do {                                              \
    const char* s_ = gA + (size_t)((h_) * 128 * 4096) + (size_t)(kt_) * 128;   \
    _Pragma("unroll")                                                          \
    for (int j_ = 0; j_ < 2; ++j_)                                             \
      __builtin_amdgcn_global_load_lds(                                        \
          (const AS1 void*)(s_ + (size_t)j_ * 64 * 4096),                      \
          (AS3 void*)(S + (c_) * 32768 + (h_) * 16384 + j_ * 8192 + wbase),    \
          16, 0, 0);                                                           \
  } while (0)
#define STAGE_B(c_, kt_, h_) do {                                              \
    const char* s_ = gB + (size_t)((h_) * 128 * 4096) + (size_t)(kt_) * 128;   \
    _Pragma("unroll")                                                          \
    for (int j_ = 0; j_ < 2; ++j_)                                             \
      __builtin_amdgcn_global_load_lds(                                        \
          (const AS1 void*)(s_ + (size_t)j_ * 64 * 4096),                      \
          (AS3 void*)(S + 65536 + (c_) * 32768 + (h_) * 16384 + j_ * 8192 + wbase), \
          16, 0, 0);                                                           \
  } while (0)

  const int swz = ((lr & 7) << 4);
  const int arow = (wp * 128 + lr) * 128;
  const int brow = (wn * 64 + lr) * 128;
  const int koff0 = (lg * 16) ^ swz;
  const int koff1 = (64 + lg * 16) ^ swz;

#define READ_A(dst_, c_, ko_, hf_)                                             \
    _Pragma("unroll")                                                          \
    for (int mi_ = 0; mi_ < 4; ++mi_)                                          \
      dst_[mi_] = *(const bf16x8*)(S + (c_) * 32768 + arow + (hf_) * 8192 +    \
                                   mi_ * 2048 + (ko_));
#define READ_B(dst_, c_, ko_)                                                  \
    _Pragma("unroll")                                                          \
    for (int ni_ = 0; ni_ < 4; ++ni_)                                          \
      dst_[ni_] = *(const bf16x8*)(S + 65536 + (c_) * 32768 + brow +           \
                                   ni_ * 2048 + (ko_));

#define PH_BAR() do { __builtin_amdgcn_sched_barrier(0);                       \
    __builtin_amdgcn_s_barrier(); __builtin_amdgcn_sched_barrier(0); } while (0)
#define LGKM0() do { asm volatile("s_waitcnt lgkmcnt(0)" ::: "memory");        \
    __builtin_amdgcn_sched_barrier(0); } while (0)
#define MFMA_Q(mlo_, af_, bf_) do { __builtin_amdgcn_s_setprio(1);             \
    _Pragma("unroll")                                                          \
    for (int mi_ = (mlo_); mi_ < (mlo_) + 4; ++mi_)                            \
      _Pragma("unroll")                                                        \
      for (int ni_ = 0; ni_ < 4; ++ni_)                                        \
        acc[mi_][ni_] = __builtin_amdgcn_mfma_f32_16x16x32_bf16(               \
            af_[mi_ - (mlo_)], bf_[ni_], acc[mi_][ni_], 0, 0, 0);              \
    __builtin_amdgcn_s_setprio(0); } while (0)

#define KT_BODY(kt_, c_, sa_, sb_, vm_) do {                                   \
    bf16x8 alo[4], ahi[4], bk0[4], bk1[4];                                     \
    READ_A(alo, c_, koff0, 0);                                                 \
    READ_B(bk0, c_, koff0);                                                    \
    if (sa_) STAGE_A((c_) ^ 1, (kt_) + 1, 0);                                  \
    PH_BAR(); LGKM0();                                                         \
    MFMA_Q(0, alo, bk0);                                                       \
    PH_BAR();                                                                  \
    READ_A(ahi, c_, koff0, 1);                                                 \
    READ_B(bk1, c_, koff1);                                                    \
    if (sa_) STAGE_A((c_) ^ 1, (kt_) + 1, 1);                                  \
    PH_BAR(); LGKM0();                                                         \
    MFMA_Q(4, ahi, bk0);                                                       \
    PH_BAR();                                                                  \
    READ_A(alo, c_, koff1, 0);                                                 \
    if (sb_) STAGE_B(c_, (kt_) + 2, 0);                                        \
    PH_BAR(); LGKM0();                                                         \
    MFMA_Q(0, alo, bk1);                                                       \
    PH_BAR();                                                                  \
    READ_A(ahi, c_, koff1, 1);                                                 \
    if (sb_) STAGE_B(c_, (kt_) + 2, 1);                                        \
    if ((vm_) == 4)      asm volatile("s_waitcnt vmcnt(4)" ::: "memory");      \
    else if ((vm_) == 0) asm volatile("s_waitcnt vmcnt(0)" ::: "memory");      \
    __builtin_amdgcn_sched_barrier(0);                                         \
    PH_BAR(); LGKM0();                                                         \
    MFMA_Q(4, ahi, bk1);                                                       \
    PH_BAR();                                                                  \
  } while (0)

  STAGE_B(0, 0, 0); STAGE_B(0, 0, 1);
  STAGE_A(0, 0, 0); STAGE_A(0, 0, 1);
  STAGE_B(1, 1, 0); STAGE_B(1, 1, 1);
  asm volatile("s_waitcnt vmcnt(4)" ::: "memory");
  __builtin_amdgcn_sched_barrier(0);
  __builtin_amdgcn_s_barrier();
  __builtin_amdgcn_sched_barrier(0);

  #pragma unroll 1
  for (int it = 0; it < 15; ++it) {
    KT_BODY(2 * it, 0, 1, 1, 4);
    KT_BODY(2 * it + 1, 1, 1, 1, 4);
  }
  KT_BODY(30, 0, 1, 0, 0);   // stages A[31]; no B[32]; drain all
  KT_BODY(31, 1, 0, 0, -1);  // pure compute
#undef KT_BODY
#undef MFMA_Q
#undef READ_A
#undef READ_B
#undef STAGE_A
#undef STAGE_B

  // epilogue: d2 = x2[m] + p2[p] - 2*dot ; per-wave 64-col window, <=2 batches
  const int wm_base = m0 + wn * 64;
  const int b_lo = wm_base / 196;
  int b_hi = (wm_base + 63) / 196;
  if (b_hi > 31) b_hi = 31;
  const bool wave_ok = (b_lo < 32);
  float x2v[4];
  int seg0[4];
  #pragma unroll
  for (int ni = 0; ni < 4; ++ni) {
    const int m = wm_base + ni * 16 + lr;  // D col = lane&15
    x2v[ni] = x2[m];
    seg0[ni] = ((m / 196) == b_lo);
  }
  const float INF = __uint_as_float(INF_BITS);
  #pragma unroll
  for (int mi = 0; mi < 8; ++mi) {
    const int prow = p0 + wp * 128 + mi * 16 + 4 * lg;  // D row = 4*(lane>>4)+j
    #pragma unroll
    for (int j = 0; j < 4; ++j) {
      const int p = prow + j;
      const float pp = p2[p];
      float ma = INF, mb = INF;
      #pragma unroll
      for (int ni = 0; ni < 4; ++ni) {
        const float d2 = x2v[ni] + pp - 2.f * acc[mi][ni][j];
        ma = fminf(ma, seg0[ni] ? d2 : INF);
        mb = fminf(mb, seg0[ni] ? INF : d2);
      }
      #pragma unroll
      for (int off = 1; off < 16; off <<= 1) {
        ma = fminf(ma, __shfl_xor(ma, off));
        mb = fminf(mb, __shfl_xor(mb, off));
      }
      if (lr == 0 && p < 2000 && wave_ok) {
        atomicMin(&outu[6400 + b_lo * 2000 + p], __float_as_uint(fmaxf(ma, 0.f)));
        if (b_hi != b_lo)
          atomicMin(&outu[6400 + b_hi * 2000 + p], __float_as_uint(fmaxf(mb, 0.f)));
      }
    }
  }
}

// ---- fused post+scores: one block per batch b ----
__global__ __launch_bounds__(512) void k_postscores(const float* __restrict__ fc_w,
                                                    float* __restrict__ out) {
  const int b = blockIdx.x;   // 32
  const int tid = threadIdx.x;
  __shared__ float sim[2000];
  for (int p = tid; p < 2000; p += 512) {
    float d2 = out[6400 + b * 2000 + p];
    float d = sqrtf(fmaxf(d2, 1e-12f));
    out[6400 + b * 2000 + p] = d;
    sim[p] = logf((d + 1.0f) / (d + 1e-7f));
  }
  __syncthreads();
  if (tid < 400) {
    const int c = tid >> 1, h = tid & 1;  // 2 threads per class, 1000 elems each
    const f32x4* sv = (const f32x4*)(sim + h * 1000);
    const f32x4* wv = (const f32x4*)(fc_w + (size_t)c * 2000 + h * 1000);
    float s = 0.f;
    #pragma unroll 4
    for (int i = 0; i < 250; ++i) {
      f32x4 a = sv[i], w4 = wv[i];
      s += a.x * w4.x + a.y * w4.y + a.z * w4.z + a.w * w4.w;
    }
    s += __shfl_xor(s, 1);
    if (h == 0) out[b * 200 + c] = s;
  }
}

extern "C" void kernel_launch(void* const* d_in, const int* in_sizes, int n_in,
                              void* d_out, int out_size, void* d_ws, size_t ws_size,
                              hipStream_t stream) {
  const float* x      = (const float*)d_in[0];  // (32, 2048, 14, 14) f32
  const float* protos = (const float*)d_in[1];  // (1, 2000, 2048) f32
  const float* fc_w   = (const float*)d_in[2];  // (200, 2000) f32
  float* out = (float*)d_out;                   // 6400 scores + 64000 min-dists

  char* wsb = (char*)d_ws;
  unsigned short* pT = (unsigned short*)wsb;              // 2048*4096B  = 8388608
  unsigned short* xT = (unsigned short*)(wsb + 8388608);  // 6400*4096B  = 26214400
  float* p2   = (float*)(wsb + 34603008);                 // 2048 f32
  float* x2   = (float*)(wsb + 34611200);                 // 6400 f32 (pad +inf)
  float* x2p  = (float*)(wsb + 34636800);                 // 32*6272 f32

  k_prep_p<<<2048, 256, 0, stream>>>(protos, pT, p2, (unsigned int*)d_out);
  k_prep_x<<<dim3(32, 33), 256, 0, stream>>>(x, xT, x2p, x2);
  k_x2r<<<25, 256, 0, stream>>>(x2p, x2);
  k_main<<<200, 512, 0, stream>>>(pT, xT, p2, x2, (unsigned int*)d_out);
  k_postscores<<<32, 512, 0, stream>>>(fc_w, out);
}

// Round 10
// 97.350 us; speedup vs baseline: 2.3283x; 1.5595x over previous
//
#include <hip/hip_runtime.h>

#define INF_BITS 0x7F800000u
#define AS1 __attribute__((address_space(1)))
#define AS3 __attribute__((address_space(3)))

typedef float f32x4 __attribute__((ext_vector_type(4)));
typedef __bf16 bf16x8 __attribute__((ext_vector_type(8)));
typedef unsigned short u16x4 __attribute__((ext_vector_type(4)));
typedef unsigned short u16x8 __attribute__((ext_vector_type(8)));
typedef unsigned int u32x4 __attribute__((ext_vector_type(4)));

static __device__ __forceinline__ unsigned short f2bf(float f) {
  unsigned int u = __float_as_uint(f);
  return (unsigned short)((u + 0x7FFFu + ((u >> 16) & 1u)) >> 16);  // RTNE
}

// ---- protos (2000x2048 f32) -> pT (2048x2048 bf16, pad rows zero) + p2 ----
// also initializes out's min-distance region to +inf (blocks 0..249)
__global__ __launch_bounds__(256) void k_prep_p(const float* __restrict__ protos,
                                                unsigned short* __restrict__ pT,
                                                float* __restrict__ p2,
                                                unsigned int* __restrict__ outu) {
  const int row = blockIdx.x;   // 2048
  const int tid = threadIdx.x;  // 256
  const int gi = row * 256 + tid;
  if (gi < 64000) outu[6400 + gi] = INF_BITS;
  __shared__ float red[4];
  float s = 0.f;
  u16x8 h = (u16x8){0, 0, 0, 0, 0, 0, 0, 0};
  if (row < 2000) {
    const float* src = protos + (size_t)row * 2048 + tid * 8;
    f32x4 a = *(const f32x4*)src;
    f32x4 c = *(const f32x4*)(src + 4);
    h = (u16x8){f2bf(a.x), f2bf(a.y), f2bf(a.z), f2bf(a.w),
                f2bf(c.x), f2bf(c.y), f2bf(c.z), f2bf(c.w)};
    s = a.x * a.x + a.y * a.y + a.z * a.z + a.w * a.w +
        c.x * c.x + c.y * c.y + c.z * c.z + c.w * c.w;
  }
  *(u16x8*)(pT + (size_t)row * 2048 + tid * 8) = h;
  #pragma unroll
  for (int off = 32; off; off >>= 1) s += __shfl_xor(s, off);
  if ((tid & 63) == 0) red[tid >> 6] = s;
  __syncthreads();
  if (tid == 0) p2[row] = red[0] + red[1] + red[2] + red[3];
}

// ---- x (b,k,n) f32 -> xT[(b*196+n)*2048+k] bf16 + x2 partials ----
// vectorized: f32x4 loads, u32x4 (16B) transposed writes. b==32 blocks do pads.
__global__ __launch_bounds__(256) void k_prep_x(const float* __restrict__ x,
                                                unsigned short* __restrict__ xT,
                                                float* __restrict__ x2p,
                                                float* __restrict__ x2) {
  const int kt = blockIdx.x;  // 32
  const int b  = blockIdx.y;  // 33: b==32 -> padding work
  const int tid = threadIdx.x;
  if (b == 32) {
    u32x4* pad = (u32x4*)(xT + (size_t)6272 * 2048);
    #pragma unroll
    for (int j = tid; j < 1024; j += 256)
      pad[kt * 1024 + j] = (u32x4){0u, 0u, 0u, 0u};
    if (kt == 0 && tid < 128) x2[6272 + tid] = __uint_as_float(INF_BITS);
    return;
  }
  __shared__ unsigned short Ls[64][204];  // stride 204: 8B-aligned u16x4 stores
  const float* src = x + ((size_t)b * 2048 + (size_t)kt * 64) * 196;
  for (int idx = tid; idx < 3136; idx += 256) {
    const int kk = idx / 49, c4 = idx - kk * 49;
    f32x4 v = *(const f32x4*)(src + (size_t)kk * 196 + c4 * 4);
    *(u16x4*)&Ls[kk][c4 * 4] = (u16x4){f2bf(v.x), f2bf(v.y), f2bf(v.z), f2bf(v.w)};
  }
  __syncthreads();
  if (tid < 196) {  // x2 partial from bf16 values (column tid)
    float s = 0.f;
    #pragma unroll
    for (int j = 0; j < 64; ++j) {
      float v = __uint_as_float((unsigned int)Ls[j][tid] << 16);
      s += v * v;
    }
    x2p[kt * 6272 + b * 196 + tid] = s;
  }
  unsigned short* dstb = xT + (size_t)b * 196 * 2048 + kt * 64;
  for (int idx = tid; idx < 1568; idx += 256) {
    const int n = idx >> 3, q = idx & 7;
    const int k0 = q * 8;
    u32x4 v;
    v.x = (unsigned int)Ls[k0 + 0][n] | ((unsigned int)Ls[k0 + 1][n] << 16);
    v.y = (unsigned int)Ls[k0 + 2][n] | ((unsigned int)Ls[k0 + 3][n] << 16);
    v.z = (unsigned int)Ls[k0 + 4][n] | ((unsigned int)Ls[k0 + 5][n] << 16);
    v.w = (unsigned int)Ls[k0 + 6][n] | ((unsigned int)Ls[k0 + 7][n] << 16);
    *(u32x4*)(dstb + (size_t)n * 2048 + k0) = v;
  }
}

__global__ void k_x2r(const float* __restrict__ x2p, float* __restrict__ x2) {
  int i = blockIdx.x * blockDim.x + threadIdx.x;
  if (i >= 6272) return;
  float s = 0.f;
  #pragma unroll
  for (int c = 0; c < 32; ++c) s += x2p[c * 6272 + i];
  x2[i] = s;
}

// ---- main GEMM: 256x256 tile, BK=64, 8 waves, m201-style 4-phase/K-tile ----
// (verbatim round-5 kernel: best measured configuration, 72 us)
__global__ __launch_bounds__(512, 2) void k_main(
    const unsigned short* __restrict__ pT, const unsigned short* __restrict__ xT,
    const float* __restrict__ p2, const float* __restrict__ x2,
    unsigned int* __restrict__ outu) {
  const int orig = blockIdx.x;
  const int wgid = (orig & 7) * 25 + (orig >> 3);
  const int ptpair = wgid / 50;
  const int rem = wgid - ptpair * 50;
  const int ptile = ptpair * 2 + (rem & 1);  // 0..7
  const int mtile = rem >> 1;                // 0..24
  const int p0 = ptile * 256;
  const int m0 = mtile * 256;
  const int tid = threadIdx.x;
  const int lane = tid & 63;
  const int w = tid >> 6;   // 8 waves
  const int wp = w >> 2;    // A half (128 rows)
  const int wn = w & 3;     // B quarter (64 rows)
  const int lr = lane & 15;
  const int lg = lane >> 4;

  __shared__ __align__(16) char S[131072];  // A[2]:0..64K, B[2]:64K..128K

  f32x4 acc[8][4];
  #pragma unroll
  for (int mi = 0; mi < 8; ++mi)
    #pragma unroll
    for (int ni = 0; ni < 4; ++ni)
      acc[mi][ni] = (f32x4){0.f, 0.f, 0.f, 0.f};

  const int rowbase = tid >> 3;                       // 0..63
  const int chunk = (tid & 7) ^ (rowbase & 7);        // involution
  const char* gA = (const char*)pT + (size_t)(p0 + rowbase) * 4096 + chunk * 16;
  const char* gB = (const char*)xT + (size_t)(m0 + rowbase) * 4096 + chunk * 16;
  const int wbase = w * 1024;

#define STAGE_A(c_, kt_, h_) do {                                              \
    const char* s_ = gA + (size_t)((h_) * 128 * 4096) + (size_t)(kt_) * 128;   \
    _Pragma("unroll")                                                          \
    for (int j_ = 0; j_ < 2; ++j_)                                             \
      __builtin_amdgcn_global_load_lds(                                        \
          (const AS1 void*)(s_ + (size_t)j_ * 64 * 4096),                      \
          (AS3 void*)(S + (c_) * 32768 + (h_) * 16384 + j_ * 8192 + wbase),    \
          16, 0, 0);                                                           \
  } while (0)
#define STAGE_B(c_, kt_, h_) do {                                              \
    const char* s_ = gB + (size_t)((h_) * 128 * 4096) + (size_t)(kt_) * 128;   \
    _Pragma("unroll")                                                          \
    for (int j_ = 0; j_ < 2; ++j_)                                             \
      __builtin_amdgcn_global_load_lds(                                        \
          (const AS1 void*)(s_ + (size_t)j_ * 64 * 4096),                      \
          (AS3 void*)(S + 65536 + (c_) * 32768 + (h_) * 16384 + j_ * 8192 + wbase), \
          16, 0, 0);                                                           \
  } while (0)

  const int swz = ((lr & 7) << 4);
  const int arow = (wp * 128 + lr) * 128;
  const int brow = (wn * 64 + lr) * 128;
  const int koff0 = (lg * 16) ^ swz;
  const int koff1 = (64 + lg * 16) ^ swz;

#define READ_A(dst_, c_, ko_, hf_)                                             \
    _Pragma("unroll")                                                          \
    for (int mi_ = 0; mi_ < 4; ++mi_)                                          \
      dst_[mi_] = *(const bf16x8*)(S + (c_) * 32768 + arow + (hf_) * 8192 +    \
                                   mi_ * 2048 + (ko_));
#define READ_B(dst_, c_, ko_)                                                  \
    _Pragma("unroll")                                                          \
    for (int ni_ = 0; ni_ < 4; ++ni_)                                          \
      dst_[ni_] = *(const bf16x8*)(S + 65536 + (c_) * 32768 + brow +           \
                                   ni_ * 2048 + (ko_));

#define PH_BAR() do { __builtin_amdgcn_sched_barrier(0);                       \
    __builtin_amdgcn_s_barrier(); __builtin_amdgcn_sched_barrier(0); } while (0)
#define LGKM0() do { asm volatile("s_waitcnt lgkmcnt(0)" ::: "memory");        \
    __builtin_amdgcn_sched_barrier(0); } while (0)
#define MFMA_Q(mlo_, af_, bf_) do { __builtin_amdgcn_s_setprio(1);             \
    _Pragma("unroll")                                                          \
    for (int mi_ = (mlo_); mi_ < (mlo_) + 4; ++mi_)                            \
      _Pragma("unroll")                                                        \
      for (int ni_ = 0; ni_ < 4; ++ni_)                                        \
        acc[mi_][ni_] = __builtin_amdgcn_mfma_f32_16x16x32_bf16(               \
            af_[mi_ - (mlo_)], bf_[ni_], acc[mi_][ni_], 0, 0, 0);              \
    __builtin_amdgcn_s_setprio(0); } while (0)

#define KT_BODY(kt_, c_, sa_, sb_, vm_) do {                                   \
    bf16x8 alo[4], ahi[4], bk0[4], bk1[4];                                     \
    READ_A(alo, c_, koff0, 0);                                                 \
    READ_B(bk0, c_, koff0);                                                    \
    if (sa_) STAGE_A((c_) ^ 1, (kt_) + 1, 0);                                  \
    PH_BAR(); LGKM0();                                                         \
    MFMA_Q(0, alo, bk0);                                                       \
    PH_BAR();                                                                  \
    READ_A(ahi, c_, koff0, 1);                                                 \
    READ_B(bk1, c_, koff1);                                                    \
    if (sa_) STAGE_A((c_) ^ 1, (kt_) + 1, 1);                                  \
    PH_BAR(); LGKM0();                                                         \
    MFMA_Q(4, ahi, bk0);                                                       \
    PH_BAR();                                                                  \
    READ_A(alo, c_, koff1, 0);                                                 \
    if (sb_) STAGE_B(c_, (kt_) + 2, 0);                                        \
    PH_BAR(); LGKM0();                                                         \
    MFMA_Q(0, alo, bk1);                                                       \
    PH_BAR();                                                                  \
    READ_A(ahi, c_, koff1, 1);                                                 \
    if (sb_) STAGE_B(c_, (kt_) + 2, 1);                                        \
    if ((vm_) == 4)      asm volatile("s_waitcnt vmcnt(4)" ::: "memory");      \
    else if ((vm_) == 0) asm volatile("s_waitcnt vmcnt(0)" ::: "memory");      \
    __builtin_amdgcn_sched_barrier(0);                                         \
    PH_BAR(); LGKM0();                                                         \
    MFMA_Q(4, ahi, bk1);                                                       \
    PH_BAR();                                                                  \
  } while (0)

  STAGE_B(0, 0, 0); STAGE_B(0, 0, 1);
  STAGE_A(0, 0, 0); STAGE_A(0, 0, 1);
  STAGE_B(1, 1, 0); STAGE_B(1, 1, 1);
  asm volatile("s_waitcnt vmcnt(4)" ::: "memory");
  __builtin_amdgcn_sched_barrier(0);
  __builtin_amdgcn_s_barrier();
  __builtin_amdgcn_sched_barrier(0);

  #pragma unroll 1
  for (int it = 0; it < 15; ++it) {
    KT_BODY(2 * it, 0, 1, 1, 4);
    KT_BODY(2 * it + 1, 1, 1, 1, 4);
  }
  KT_BODY(30, 0, 1, 0, 0);   // stages A[31]; no B[32]; drain all
  KT_BODY(31, 1, 0, 0, -1);  // pure compute
#undef KT_BODY
#undef MFMA_Q
#undef READ_A
#undef READ_B
#undef STAGE_A
#undef STAGE_B

  // epilogue: d2 = x2[m] + p2[p] - 2*dot ; per-wave 64-col window, <=2 batches
  const int wm_base = m0 + wn * 64;
  const int b_lo = wm_base / 196;
  int b_hi = (wm_base + 63) / 196;
  if (b_hi > 31) b_hi = 31;
  const bool wave_ok = (b_lo < 32);
  float x2v[4];
  int seg0[4];
  #pragma unroll
  for (int ni = 0; ni < 4; ++ni) {
    const int m = wm_base + ni * 16 + lr;  // D col = lane&15
    x2v[ni] = x2[m];
    seg0[ni] = ((m / 196) == b_lo);
  }
  const float INF = __uint_as_float(INF_BITS);
  #pragma unroll
  for (int mi = 0; mi < 8; ++mi) {
    const int prow = p0 + wp * 128 + mi * 16 + 4 * lg;  // D row = 4*(lane>>4)+j
    #pragma unroll
    for (int j = 0; j < 4; ++j) {
      const int p = prow + j;
      const float pp = p2[p];
      float ma = INF, mb = INF;
      #pragma unroll
      for (int ni = 0; ni < 4; ++ni) {
        const float d2 = x2v[ni] + pp - 2.f * acc[mi][ni][j];
        ma = fminf(ma, seg0[ni] ? d2 : INF);
        mb = fminf(mb, seg0[ni] ? INF : d2);
      }
      #pragma unroll
      for (int off = 1; off < 16; off <<= 1) {
        ma = fminf(ma, __shfl_xor(ma, off));
        mb = fminf(mb, __shfl_xor(mb, off));
      }
      if (lr == 0 && p < 2000 && wave_ok) {
        atomicMin(&outu[6400 + b_lo * 2000 + p], __float_as_uint(fmaxf(ma, 0.f)));
        if (b_hi != b_lo)
          atomicMin(&outu[6400 + b_hi * 2000 + p], __float_as_uint(fmaxf(mb, 0.f)));
      }
    }
  }
}

// ---- post: d = sqrt(max(d2,1e-12)) in place; sim -> simbuf ----
__global__ void k_post(float* __restrict__ out, float* __restrict__ simbuf) {
  int i = blockIdx.x * blockDim.x + threadIdx.x;
  if (i >= 64000) return;
  float d2 = out[6400 + i];
  float d = sqrtf(fmaxf(d2, 1e-12f));
  out[6400 + i] = d;
  simbuf[i] = logf((d + 1.0f) / (d + 1e-7f));
}

// ---- scores: one wave per (b, class) pair ----
__global__ __launch_bounds__(256) void k_scores(const float* __restrict__ fc_w,
                                                const float* __restrict__ simbuf,
                                                float* __restrict__ out) {
  const int id = blockIdx.x * 4 + (threadIdx.x >> 6);  // 0..6399
  const int lane = threadIdx.x & 63;
  const int b = id / 200;
  const int c = id - b * 200;
  const f32x4* sv = (const f32x4*)(simbuf + (size_t)b * 2000);
  const f32x4* wv = (const f32x4*)(fc_w + (size_t)c * 2000);
  float s = 0.f;
  #pragma unroll
  for (int it = 0; it < 8; ++it) {
    int i = lane + it * 64;
    if (i < 500) {
      f32x4 a = sv[i], w4 = wv[i];
      s += a.x * w4.x + a.y * w4.y + a.z * w4.z + a.w * w4.w;
    }
  }
  #pragma unroll
  for (int off = 32; off; off >>= 1) s += __shfl_xor(s, off);
  if (lane == 0) out[b * 200 + c] = s;
}

extern "C" void kernel_launch(void* const* d_in, const int* in_sizes, int n_in,
                              void* d_out, int out_size, void* d_ws, size_t ws_size,
                              hipStream_t stream) {
  const float* x      = (const float*)d_in[0];  // (32, 2048, 14, 14) f32
  const float* protos = (const float*)d_in[1];  // (1, 2000, 2048) f32
  const float* fc_w   = (const float*)d_in[2];  // (200, 2000) f32
  float* out = (float*)d_out;                   // 6400 scores + 64000 min-dists

  char* wsb = (char*)d_ws;
  unsigned short* pT = (unsigned short*)wsb;              // 2048*4096B  = 8388608
  unsigned short* xT = (unsigned short*)(wsb + 8388608);  // 6400*4096B  = 26214400
  float* p2   = (float*)(wsb + 34603008);                 // 2048 f32
  float* x2   = (float*)(wsb + 34611200);                 // 6400 f32 (pad +inf)
  float* x2p  = (float*)(wsb + 34636800);                 // 32*6272 f32
  float* simb = (float*)(wsb + 34636800);                 // aliases x2p (dead after k_x2r)

  k_prep_p<<<2048, 256, 0, stream>>>(protos, pT, p2, (unsigned int*)d_out);
  k_prep_x<<<dim3(32, 33), 256, 0, stream>>>(x, xT, x2p, x2);
  k_x2r<<<25, 256, 0, stream>>>(x2p, x2);
  k_main<<<200, 512, 0, stream>>>(pT, xT, p2, x2, (unsigned int*)d_out);
  k_post<<<250, 256, 0, stream>>>(out, simb);
  k_scores<<<1600, 256, 0, stream>>>(fc_w, simb, out);
}